// Round 2
// baseline (1342.821 us; speedup 1.0000x reference)
//
#include <hip/hip_runtime.h>
#include <hip/hip_fp16.h>

// FeatureGrid: trilinear interp of N points into (C=32, 128^3) f32 grid.
// v3: fp16 (S,C) workspace (round-1 win) + z-slab point binning so the
// random corner gathers become L2-resident (2 MiB working set per bucket)
// instead of L3-resident (128 MiB). Per-point math order unchanged ->
// bitwise-identical output to v2.

constexpr int   GD      = 128;                         // grid dim per axis
constexpr long long SPATIAL = (long long)GD * GD * GD; // 2097152
constexpr int   FD      = 32;                          // channels
constexpr float PLO     = -10.0f;
constexpr float PHI     = 10.0f;
constexpr int   NBUCKET = 129;                         // z0 in [-1,127] -> z0+1

typedef float nfloat4 __attribute__((ext_vector_type(4)));

__device__ __forceinline__ int z_bucket(float pz) {
    const float cz = 2.0f * (pz - PLO) / (PHI - PLO) - 1.0f;
    const float fz = ((cz + 1.0f) * GD - 1.0f) * 0.5f;
    int zb = (int)floorf(fz) + 1;
    return min(max(zb, 0), NBUCKET - 1);
}

// ---------------- transpose+convert (C,S) f32 -> (S,C) fp16 ----------------
__global__ __launch_bounds__(256) void transpose_feat_h(
    const float* __restrict__ f, __half* __restrict__ o) {
    __shared__ float lds[64][FD + 1];
    const int t  = threadIdx.x;
    const long long s0 = (long long)blockIdx.x * 64;
    const int sl = t & 63;   // spatial within tile
    const int cq = t >> 6;   // 0..3
#pragma unroll
    for (int it = 0; it < 8; ++it) {
        const int c = it * 4 + cq;
        lds[sl][c] =
            __builtin_nontemporal_load(f + (size_t)c * SPATIAL + s0 + sl);
    }
    __syncthreads();
    const int c0 = (t & 15) * 2;  // channel pair
    const int sw = t >> 4;        // 0..15
#pragma unroll
    for (int it = 0; it < 4; ++it) {
        const int s = sw + it * 16;
        __half2 h;
        h.x = __float2half(lds[s][c0]);
        h.y = __float2half(lds[s][c0 + 1]);
        *reinterpret_cast<__half2*>(o + (size_t)(s0 + s) * FD + c0) = h;
    }
}

// ---------------- pass 1: z-slab histogram ----------------
__global__ __launch_bounds__(256) void hist_kernel(
    const float* __restrict__ x, int* __restrict__ hist, int npts) {
    __shared__ int h[NBUCKET];
    const int t = threadIdx.x;
    if (t < NBUCKET) h[t] = 0;
    __syncthreads();
    const int n = blockIdx.x * 256 + t;
    if (n < npts) {
        const int zb = z_bucket(x[3 * n + 2]);
        atomicAdd(&h[zb], 1);
    }
    __syncthreads();
    if (t < NBUCKET && h[t]) atomicAdd(&hist[t], h[t]);
}

// ---------------- pass 2: exclusive scan (129 bins, trivial) ----------------
__global__ void scan_hist(const int* __restrict__ hist,
                          int* __restrict__ cursor) {
    if (threadIdx.x == 0 && blockIdx.x == 0) {
        int run = 0;
        for (int b = 0; b < NBUCKET; ++b) {
            cursor[b] = run;
            run += hist[b];
        }
    }
}

// ---------------- pass 3: scatter points into bucket order ----------------
__global__ __launch_bounds__(256) void scatter_kernel(
    const float* __restrict__ x, int* __restrict__ cursor,
    nfloat4* __restrict__ binned, int npts) {
    const int n = blockIdx.x * 256 + threadIdx.x;
    if (n >= npts) return;
    const float px = x[3 * n + 0];
    const float py = x[3 * n + 1];
    const float pz = x[3 * n + 2];
    const int zb = z_bucket(pz);
    const int pos = atomicAdd(&cursor[zb], 1);
    nfloat4 rec = {px, py, pz, __int_as_float(n)};
    binned[pos] = rec;
}

// ---------------- pass 4: gather, bucket order, fp16 feature ----------------
// 4 threads per point; each owns 8 channels (16-B load per corner).
__global__ __launch_bounds__(256) void trilerp_b(
    const nfloat4* __restrict__ binned, const __half* __restrict__ ft,
    float* __restrict__ out, int npts) {
    const int tid = blockIdx.x * 256 + threadIdx.x;
    const int i = tid >> 2;
    if (i >= npts) return;
    const int j = tid & 3;  // channel octet

    const nfloat4 rec = binned[i];
    const float px = rec.x, py = rec.y, pz = rec.z;
    const int n = __float_as_int(rec.w);

    // match reference arithmetic order
    const float cx = 2.0f * (px - PLO) / (PHI - PLO) - 1.0f;
    const float cy = 2.0f * (py - PLO) / (PHI - PLO) - 1.0f;
    const float cz = 2.0f * (pz - PLO) / (PHI - PLO) - 1.0f;
    const float fx = ((cx + 1.0f) * GD - 1.0f) * 0.5f;
    const float fy = ((cy + 1.0f) * GD - 1.0f) * 0.5f;
    const float fz = ((cz + 1.0f) * GD - 1.0f) * 0.5f;

    const float x0f = floorf(fx), y0f = floorf(fy), z0f = floorf(fz);
    const float wx = fx - x0f, wy = fy - y0f, wz = fz - z0f;
    const int x0 = (int)x0f, y0 = (int)y0f, z0 = (int)z0f;

    float acc[8] = {0.f, 0.f, 0.f, 0.f, 0.f, 0.f, 0.f, 0.f};
#pragma unroll
    for (int dz = 0; dz < 2; ++dz) {
#pragma unroll
        for (int dy = 0; dy < 2; ++dy) {
#pragma unroll
            for (int dx = 0; dx < 2; ++dx) {
                const int xi = x0 + dx, yi = y0 + dy, zi = z0 + dz;
                const bool valid = ((unsigned)xi < (unsigned)GD) &
                                   ((unsigned)yi < (unsigned)GD) &
                                   ((unsigned)zi < (unsigned)GD);
                float w = (dx ? wx : 1.0f - wx) * (dy ? wy : 1.0f - wy) *
                          (dz ? wz : 1.0f - wz);
                w = valid ? w : 0.0f;
                const int xc = min(max(xi, 0), GD - 1);
                const int yc = min(max(yi, 0), GD - 1);
                const int zc = min(max(zi, 0), GD - 1);
                const size_t idx = (size_t)(zc * GD + yc) * GD + xc;
                const nfloat4 raw = *reinterpret_cast<const nfloat4*>(
                    ft + idx * FD + j * 8);
                const __half2* h2 = reinterpret_cast<const __half2*>(&raw);
#pragma unroll
                for (int k = 0; k < 4; ++k) {
                    const float2 fv = __half22float2(h2[k]);
                    acc[2 * k + 0] = fmaf(fv.x, w, acc[2 * k + 0]);
                    acc[2 * k + 1] = fmaf(fv.y, w, acc[2 * k + 1]);
                }
            }
        }
    }
    float* op = out + (size_t)n * FD + j * 8;
    nfloat4 o0 = {acc[0], acc[1], acc[2], acc[3]};
    nfloat4 o1 = {acc[4], acc[5], acc[6], acc[7]};
    __builtin_nontemporal_store(o0, reinterpret_cast<nfloat4*>(op));
    __builtin_nontemporal_store(o1, reinterpret_cast<nfloat4*>(op) + 1);
}

// ---------------- fallback: un-binned gather (round-1 kernel) ----------------
__global__ __launch_bounds__(256) void trilerp_h(
    const float* __restrict__ x, const __half* __restrict__ ft,
    float* __restrict__ out, int npts) {
    const int tid = blockIdx.x * 256 + threadIdx.x;
    const int n = tid >> 2;
    if (n >= npts) return;
    const int j = tid & 3;

    const float px = x[3 * n + 0];
    const float py = x[3 * n + 1];
    const float pz = x[3 * n + 2];
    const float cx = 2.0f * (px - PLO) / (PHI - PLO) - 1.0f;
    const float cy = 2.0f * (py - PLO) / (PHI - PLO) - 1.0f;
    const float cz = 2.0f * (pz - PLO) / (PHI - PLO) - 1.0f;
    const float fx = ((cx + 1.0f) * GD - 1.0f) * 0.5f;
    const float fy = ((cy + 1.0f) * GD - 1.0f) * 0.5f;
    const float fz = ((cz + 1.0f) * GD - 1.0f) * 0.5f;
    const float x0f = floorf(fx), y0f = floorf(fy), z0f = floorf(fz);
    const float wx = fx - x0f, wy = fy - y0f, wz = fz - z0f;
    const int x0 = (int)x0f, y0 = (int)y0f, z0 = (int)z0f;

    float acc[8] = {0.f, 0.f, 0.f, 0.f, 0.f, 0.f, 0.f, 0.f};
#pragma unroll
    for (int dz = 0; dz < 2; ++dz)
#pragma unroll
        for (int dy = 0; dy < 2; ++dy)
#pragma unroll
            for (int dx = 0; dx < 2; ++dx) {
                const int xi = x0 + dx, yi = y0 + dy, zi = z0 + dz;
                const bool valid = ((unsigned)xi < (unsigned)GD) &
                                   ((unsigned)yi < (unsigned)GD) &
                                   ((unsigned)zi < (unsigned)GD);
                float w = (dx ? wx : 1.0f - wx) * (dy ? wy : 1.0f - wy) *
                          (dz ? wz : 1.0f - wz);
                w = valid ? w : 0.0f;
                const int xc = min(max(xi, 0), GD - 1);
                const int yc = min(max(yi, 0), GD - 1);
                const int zc = min(max(zi, 0), GD - 1);
                const size_t idx = (size_t)(zc * GD + yc) * GD + xc;
                const nfloat4 raw = *reinterpret_cast<const nfloat4*>(
                    ft + idx * FD + j * 8);
                const __half2* h2 = reinterpret_cast<const __half2*>(&raw);
#pragma unroll
                for (int k = 0; k < 4; ++k) {
                    const float2 fv = __half22float2(h2[k]);
                    acc[2 * k + 0] = fmaf(fv.x, w, acc[2 * k + 0]);
                    acc[2 * k + 1] = fmaf(fv.y, w, acc[2 * k + 1]);
                }
            }
    float* op = out + (size_t)n * FD + j * 8;
    nfloat4 o0 = {acc[0], acc[1], acc[2], acc[3]};
    nfloat4 o1 = {acc[4], acc[5], acc[6], acc[7]};
    __builtin_nontemporal_store(o0, reinterpret_cast<nfloat4*>(op));
    __builtin_nontemporal_store(o1, reinterpret_cast<nfloat4*>(op) + 1);
}

// ---------------- fallback: direct gather in (C,S) layout ----------------
__global__ __launch_bounds__(256) void trilerp_direct(
    const float* __restrict__ x, const float* __restrict__ f,
    float* __restrict__ out, int npts) {
    const int tid = blockIdx.x * 256 + threadIdx.x;
    const int n = tid >> 3;
    if (n >= npts) return;
    const int j = tid & 7;

    const float px = x[3 * n + 0];
    const float py = x[3 * n + 1];
    const float pz = x[3 * n + 2];
    const float cx = 2.0f * (px - PLO) / (PHI - PLO) - 1.0f;
    const float cy = 2.0f * (py - PLO) / (PHI - PLO) - 1.0f;
    const float cz = 2.0f * (pz - PLO) / (PHI - PLO) - 1.0f;
    const float fx = ((cx + 1.0f) * GD - 1.0f) * 0.5f;
    const float fy = ((cy + 1.0f) * GD - 1.0f) * 0.5f;
    const float fz = ((cz + 1.0f) * GD - 1.0f) * 0.5f;
    const float x0f = floorf(fx), y0f = floorf(fy), z0f = floorf(fz);
    const float wx = fx - x0f, wy = fy - y0f, wz = fz - z0f;
    const int x0 = (int)x0f, y0 = (int)y0f, z0 = (int)z0f;

    float acc[4] = {0.f, 0.f, 0.f, 0.f};
#pragma unroll
    for (int dz = 0; dz < 2; ++dz)
#pragma unroll
        for (int dy = 0; dy < 2; ++dy)
#pragma unroll
            for (int dx = 0; dx < 2; ++dx) {
                const int xi = x0 + dx, yi = y0 + dy, zi = z0 + dz;
                const bool valid = ((unsigned)xi < (unsigned)GD) &
                                   ((unsigned)yi < (unsigned)GD) &
                                   ((unsigned)zi < (unsigned)GD);
                float w = (dx ? wx : 1.0f - wx) * (dy ? wy : 1.0f - wy) *
                          (dz ? wz : 1.0f - wz);
                w = valid ? w : 0.0f;
                const int xc = min(max(xi, 0), GD - 1);
                const int yc = min(max(yi, 0), GD - 1);
                const int zc = min(max(zi, 0), GD - 1);
                const size_t idx = (size_t)(zc * GD + yc) * GD + xc;
#pragma unroll
                for (int k = 0; k < 4; ++k)
                    acc[k] = fmaf(f[(size_t)(j * 4 + k) * SPATIAL + idx], w, acc[k]);
            }
#pragma unroll
    for (int k = 0; k < 4; ++k) out[(size_t)n * FD + j * 4 + k] = acc[k];
}

extern "C" void kernel_launch(void* const* d_in, const int* in_sizes, int n_in,
                              void* d_out, int out_size, void* d_ws, size_t ws_size,
                              hipStream_t stream) {
    const float* x    = (const float*)d_in[0];
    const float* feat = (const float*)d_in[1];
    float*       out  = (float*)d_out;
    const int npts = in_sizes[0] / 3;

    const size_t FTH_BYTES    = (size_t)SPATIAL * FD * sizeof(__half); // 128 MiB
    const size_t BINNED_OFF   = FTH_BYTES;
    const size_t BINNED_BYTES = (size_t)npts * 16;
    const size_t META_OFF     = BINNED_OFF + ((BINNED_BYTES + 255) & ~(size_t)255);
    const size_t META_BYTES   = 2 * NBUCKET * sizeof(int);
    const size_t need_binned  = META_OFF + META_BYTES;

    const int pblocks = (npts + 255) / 256;      // 1 thread / point
    const int gblocks = (npts * 4 + 255) / 256;  // 4 threads / point

    if (ws_size >= need_binned) {
        __half*  fth    = (__half*)d_ws;
        nfloat4* binned = (nfloat4*)((char*)d_ws + BINNED_OFF);
        int*     hist   = (int*)((char*)d_ws + META_OFF);
        int*     cursor = hist + NBUCKET;

        hipMemsetAsync(hist, 0, NBUCKET * sizeof(int), stream);
        transpose_feat_h<<<(int)(SPATIAL / 64), 256, 0, stream>>>(feat, fth);
        hist_kernel<<<pblocks, 256, 0, stream>>>(x, hist, npts);
        scan_hist<<<1, 64, 0, stream>>>(hist, cursor);
        scatter_kernel<<<pblocks, 256, 0, stream>>>(x, cursor, binned, npts);
        trilerp_b<<<gblocks, 256, 0, stream>>>(binned, fth, out, npts);
    } else if (ws_size >= FTH_BYTES) {
        __half* fth = (__half*)d_ws;
        transpose_feat_h<<<(int)(SPATIAL / 64), 256, 0, stream>>>(feat, fth);
        trilerp_h<<<gblocks, 256, 0, stream>>>(x, fth, out, npts);
    } else {
        const int dblocks = (npts * 8 + 255) / 256;
        trilerp_direct<<<dblocks, 256, 0, stream>>>(x, feat, out, npts);
    }
}

// Round 3
// 508.057 us; speedup vs baseline: 2.6431x; 2.6431x over previous
//
#include <hip/hip_runtime.h>
#include <hip/hip_fp16.h>

// FeatureGrid: trilinear interp of N points into (C=32, 128^3) f32 grid.
// v4: fp16 (S,C) workspace + z-slab binning via DETERMINISTIC counting sort
// (per-block LDS hist -> cross-block scan -> rank via LDS atomics).
// Round-2's global-atomic scatter (129 cursors, 797us of contention) is gone.
// Per-point math order unchanged -> bitwise-identical output to v2/v3.

constexpr int   GD      = 128;                         // grid dim per axis
constexpr long long SPATIAL = (long long)GD * GD * GD; // 2097152
constexpr int   FD      = 32;                          // channels
constexpr float PLO     = -10.0f;
constexpr float PHI     = 10.0f;
constexpr int   NBUCKET = 129;                         // z0 in [-1,127] -> z0+1

typedef float nfloat4 __attribute__((ext_vector_type(4)));

__device__ __forceinline__ int z_bucket(float pz) {
    const float cz = 2.0f * (pz - PLO) / (PHI - PLO) - 1.0f;
    const float fz = ((cz + 1.0f) * GD - 1.0f) * 0.5f;
    int zb = (int)floorf(fz) + 1;
    return min(max(zb, 0), NBUCKET - 1);
}

// ---------------- transpose+convert (C,S) f32 -> (S,C) fp16 ----------------
__global__ __launch_bounds__(256) void transpose_feat_h(
    const float* __restrict__ f, __half* __restrict__ o) {
    __shared__ float lds[64][FD + 1];
    const int t  = threadIdx.x;
    const long long s0 = (long long)blockIdx.x * 64;
    const int sl = t & 63;   // spatial within tile
    const int cq = t >> 6;   // 0..3
#pragma unroll
    for (int it = 0; it < 8; ++it) {
        const int c = it * 4 + cq;
        lds[sl][c] =
            __builtin_nontemporal_load(f + (size_t)c * SPATIAL + s0 + sl);
    }
    __syncthreads();
    const int c0 = (t & 15) * 2;  // channel pair
    const int sw = t >> 4;        // 0..15
#pragma unroll
    for (int it = 0; it < 4; ++it) {
        const int s = sw + it * 16;
        __half2 h;
        h.x = __float2half(lds[s][c0]);
        h.y = __float2half(lds[s][c0 + 1]);
        *reinterpret_cast<__half2*>(o + (size_t)(s0 + s) * FD + c0) = h;
    }
}

// ---------------- pass A: per-block z-slab histogram ----------------
// blockHist layout is bin-major: blockHist[bin * nblocks + block]
__global__ __launch_bounds__(256) void hist_blocks(
    const float* __restrict__ x, int* __restrict__ blockHist,
    int npts, int nblocks) {
    __shared__ int h[NBUCKET];
    const int t = threadIdx.x;
    if (t < NBUCKET) h[t] = 0;
    __syncthreads();
    const int n = blockIdx.x * 256 + t;
    if (n < npts) atomicAdd(&h[z_bucket(x[3 * n + 2])], 1);
    __syncthreads();
    if (t < NBUCKET)
        blockHist[(size_t)t * nblocks + blockIdx.x] = h[t];
}

// ---------------- pass B1: exclusive scan within each bin row ----------------
// one block per bin; chunked Hillis-Steele over nblocks entries (in place).
__global__ __launch_bounds__(256) void scan_bins(
    int* __restrict__ blockHist, int* __restrict__ binSum, int nblocks) {
    __shared__ int tmp[256];
    const int bin = blockIdx.x;
    int* row = blockHist + (size_t)bin * nblocks;
    const int t = threadIdx.x;
    int carry = 0;
    for (int base = 0; base < nblocks; base += 256) {
        const int i = base + t;
        const int v = (i < nblocks) ? row[i] : 0;
        tmp[t] = v;
        __syncthreads();
        int run = v;
        for (int off = 1; off < 256; off <<= 1) {
            const int add = (t >= off) ? tmp[t - off] : 0;
            __syncthreads();
            run += add;
            tmp[t] = run;
            __syncthreads();
        }
        if (i < nblocks) row[i] = carry + (run - v);  // exclusive + carry
        carry += tmp[255];
        __syncthreads();
    }
    if (t == 0) binSum[bin] = carry;
}

// ---------------- pass B2: scan bin totals (129 entries, trivial) ----------
__global__ void scan_bin_totals(const int* __restrict__ binSum,
                                int* __restrict__ binBase) {
    if (threadIdx.x == 0 && blockIdx.x == 0) {
        int run = 0;
        for (int b = 0; b < NBUCKET; ++b) {
            binBase[b] = run;
            run += binSum[b];
        }
    }
}

// ---------------- pass C: atomic-free global scatter ----------------
// rank within (block,bin) via LDS atomics (~2 threads/bin -> free);
// destination fully determined -> no global atomics.
__global__ __launch_bounds__(256) void scatter_det(
    const float* __restrict__ x, const int* __restrict__ blockHist,
    const int* __restrict__ binBase, nfloat4* __restrict__ binned,
    int npts, int nblocks) {
    __shared__ int h[NBUCKET];
    const int t = threadIdx.x;
    if (t < NBUCKET) h[t] = 0;
    __syncthreads();
    const int n = blockIdx.x * 256 + t;
    if (n >= npts) return;
    const float px = x[3 * n + 0];
    const float py = x[3 * n + 1];
    const float pz = x[3 * n + 2];
    const int bin = z_bucket(pz);
    const int rank = atomicAdd(&h[bin], 1);
    const int dest =
        binBase[bin] + blockHist[(size_t)bin * nblocks + blockIdx.x] + rank;
    nfloat4 rec = {px, py, pz, __int_as_float(n)};
    binned[dest] = rec;
}

// ---------------- pass D: gather, bucket order, fp16 feature ----------------
// 4 threads per point; each owns 8 channels (16-B load per corner).
__global__ __launch_bounds__(256) void trilerp_b(
    const nfloat4* __restrict__ binned, const __half* __restrict__ ft,
    float* __restrict__ out, int npts) {
    const int tid = blockIdx.x * 256 + threadIdx.x;
    const int i = tid >> 2;
    if (i >= npts) return;
    const int j = tid & 3;  // channel octet

    const nfloat4 rec = binned[i];
    const float px = rec.x, py = rec.y, pz = rec.z;
    const int n = __float_as_int(rec.w);

    // match reference arithmetic order
    const float cx = 2.0f * (px - PLO) / (PHI - PLO) - 1.0f;
    const float cy = 2.0f * (py - PLO) / (PHI - PLO) - 1.0f;
    const float cz = 2.0f * (pz - PLO) / (PHI - PLO) - 1.0f;
    const float fx = ((cx + 1.0f) * GD - 1.0f) * 0.5f;
    const float fy = ((cy + 1.0f) * GD - 1.0f) * 0.5f;
    const float fz = ((cz + 1.0f) * GD - 1.0f) * 0.5f;

    const float x0f = floorf(fx), y0f = floorf(fy), z0f = floorf(fz);
    const float wx = fx - x0f, wy = fy - y0f, wz = fz - z0f;
    const int x0 = (int)x0f, y0 = (int)y0f, z0 = (int)z0f;

    float acc[8] = {0.f, 0.f, 0.f, 0.f, 0.f, 0.f, 0.f, 0.f};
#pragma unroll
    for (int dz = 0; dz < 2; ++dz) {
#pragma unroll
        for (int dy = 0; dy < 2; ++dy) {
#pragma unroll
            for (int dx = 0; dx < 2; ++dx) {
                const int xi = x0 + dx, yi = y0 + dy, zi = z0 + dz;
                const bool valid = ((unsigned)xi < (unsigned)GD) &
                                   ((unsigned)yi < (unsigned)GD) &
                                   ((unsigned)zi < (unsigned)GD);
                float w = (dx ? wx : 1.0f - wx) * (dy ? wy : 1.0f - wy) *
                          (dz ? wz : 1.0f - wz);
                w = valid ? w : 0.0f;
                const int xc = min(max(xi, 0), GD - 1);
                const int yc = min(max(yi, 0), GD - 1);
                const int zc = min(max(zi, 0), GD - 1);
                const size_t idx = (size_t)(zc * GD + yc) * GD + xc;
                const nfloat4 raw = *reinterpret_cast<const nfloat4*>(
                    ft + idx * FD + j * 8);
                const __half2* h2 = reinterpret_cast<const __half2*>(&raw);
#pragma unroll
                for (int k = 0; k < 4; ++k) {
                    const float2 fv = __half22float2(h2[k]);
                    acc[2 * k + 0] = fmaf(fv.x, w, acc[2 * k + 0]);
                    acc[2 * k + 1] = fmaf(fv.y, w, acc[2 * k + 1]);
                }
            }
        }
    }
    float* op = out + (size_t)n * FD + j * 8;
    nfloat4 o0 = {acc[0], acc[1], acc[2], acc[3]};
    nfloat4 o1 = {acc[4], acc[5], acc[6], acc[7]};
    __builtin_nontemporal_store(o0, reinterpret_cast<nfloat4*>(op));
    __builtin_nontemporal_store(o1, reinterpret_cast<nfloat4*>(op) + 1);
}

// ---------------- fallback: un-binned gather (round-1 kernel) ----------------
__global__ __launch_bounds__(256) void trilerp_h(
    const float* __restrict__ x, const __half* __restrict__ ft,
    float* __restrict__ out, int npts) {
    const int tid = blockIdx.x * 256 + threadIdx.x;
    const int n = tid >> 2;
    if (n >= npts) return;
    const int j = tid & 3;

    const float px = x[3 * n + 0];
    const float py = x[3 * n + 1];
    const float pz = x[3 * n + 2];
    const float cx = 2.0f * (px - PLO) / (PHI - PLO) - 1.0f;
    const float cy = 2.0f * (py - PLO) / (PHI - PLO) - 1.0f;
    const float cz = 2.0f * (pz - PLO) / (PHI - PLO) - 1.0f;
    const float fx = ((cx + 1.0f) * GD - 1.0f) * 0.5f;
    const float fy = ((cy + 1.0f) * GD - 1.0f) * 0.5f;
    const float fz = ((cz + 1.0f) * GD - 1.0f) * 0.5f;
    const float x0f = floorf(fx), y0f = floorf(fy), z0f = floorf(fz);
    const float wx = fx - x0f, wy = fy - y0f, wz = fz - z0f;
    const int x0 = (int)x0f, y0 = (int)y0f, z0 = (int)z0f;

    float acc[8] = {0.f, 0.f, 0.f, 0.f, 0.f, 0.f, 0.f, 0.f};
#pragma unroll
    for (int dz = 0; dz < 2; ++dz)
#pragma unroll
        for (int dy = 0; dy < 2; ++dy)
#pragma unroll
            for (int dx = 0; dx < 2; ++dx) {
                const int xi = x0 + dx, yi = y0 + dy, zi = z0 + dz;
                const bool valid = ((unsigned)xi < (unsigned)GD) &
                                   ((unsigned)yi < (unsigned)GD) &
                                   ((unsigned)zi < (unsigned)GD);
                float w = (dx ? wx : 1.0f - wx) * (dy ? wy : 1.0f - wy) *
                          (dz ? wz : 1.0f - wz);
                w = valid ? w : 0.0f;
                const int xc = min(max(xi, 0), GD - 1);
                const int yc = min(max(yi, 0), GD - 1);
                const int zc = min(max(zi, 0), GD - 1);
                const size_t idx = (size_t)(zc * GD + yc) * GD + xc;
                const nfloat4 raw = *reinterpret_cast<const nfloat4*>(
                    ft + idx * FD + j * 8);
                const __half2* h2 = reinterpret_cast<const __half2*>(&raw);
#pragma unroll
                for (int k = 0; k < 4; ++k) {
                    const float2 fv = __half22float2(h2[k]);
                    acc[2 * k + 0] = fmaf(fv.x, w, acc[2 * k + 0]);
                    acc[2 * k + 1] = fmaf(fv.y, w, acc[2 * k + 1]);
                }
            }
    float* op = out + (size_t)n * FD + j * 8;
    nfloat4 o0 = {acc[0], acc[1], acc[2], acc[3]};
    nfloat4 o1 = {acc[4], acc[5], acc[6], acc[7]};
    __builtin_nontemporal_store(o0, reinterpret_cast<nfloat4*>(op));
    __builtin_nontemporal_store(o1, reinterpret_cast<nfloat4*>(op) + 1);
}

// ---------------- fallback: direct gather in (C,S) layout ----------------
__global__ __launch_bounds__(256) void trilerp_direct(
    const float* __restrict__ x, const float* __restrict__ f,
    float* __restrict__ out, int npts) {
    const int tid = blockIdx.x * 256 + threadIdx.x;
    const int n = tid >> 3;
    if (n >= npts) return;
    const int j = tid & 7;

    const float px = x[3 * n + 0];
    const float py = x[3 * n + 1];
    const float pz = x[3 * n + 2];
    const float cx = 2.0f * (px - PLO) / (PHI - PLO) - 1.0f;
    const float cy = 2.0f * (py - PLO) / (PHI - PLO) - 1.0f;
    const float cz = 2.0f * (pz - PLO) / (PHI - PLO) - 1.0f;
    const float fx = ((cx + 1.0f) * GD - 1.0f) * 0.5f;
    const float fy = ((cy + 1.0f) * GD - 1.0f) * 0.5f;
    const float fz = ((cz + 1.0f) * GD - 1.0f) * 0.5f;
    const float x0f = floorf(fx), y0f = floorf(fy), z0f = floorf(fz);
    const float wx = fx - x0f, wy = fy - y0f, wz = fz - z0f;
    const int x0 = (int)x0f, y0 = (int)y0f, z0 = (int)z0f;

    float acc[4] = {0.f, 0.f, 0.f, 0.f};
#pragma unroll
    for (int dz = 0; dz < 2; ++dz)
#pragma unroll
        for (int dy = 0; dy < 2; ++dy)
#pragma unroll
            for (int dx = 0; dx < 2; ++dx) {
                const int xi = x0 + dx, yi = y0 + dy, zi = z0 + dz;
                const bool valid = ((unsigned)xi < (unsigned)GD) &
                                   ((unsigned)yi < (unsigned)GD) &
                                   ((unsigned)zi < (unsigned)GD);
                float w = (dx ? wx : 1.0f - wx) * (dy ? wy : 1.0f - wy) *
                          (dz ? wz : 1.0f - wz);
                w = valid ? w : 0.0f;
                const int xc = min(max(xi, 0), GD - 1);
                const int yc = min(max(yi, 0), GD - 1);
                const int zc = min(max(zi, 0), GD - 1);
                const size_t idx = (size_t)(zc * GD + yc) * GD + xc;
#pragma unroll
                for (int k = 0; k < 4; ++k)
                    acc[k] = fmaf(f[(size_t)(j * 4 + k) * SPATIAL + idx], w, acc[k]);
            }
#pragma unroll
    for (int k = 0; k < 4; ++k) out[(size_t)n * FD + j * 4 + k] = acc[k];
}

extern "C" void kernel_launch(void* const* d_in, const int* in_sizes, int n_in,
                              void* d_out, int out_size, void* d_ws, size_t ws_size,
                              hipStream_t stream) {
    const float* x    = (const float*)d_in[0];
    const float* feat = (const float*)d_in[1];
    float*       out  = (float*)d_out;
    const int npts = in_sizes[0] / 3;

    const int nb      = (npts + 255) / 256;      // point blocks
    const int gblocks = (npts * 4 + 255) / 256;  // 4 threads / point

    const size_t FTH_BYTES    = (size_t)SPATIAL * FD * sizeof(__half); // 128 MiB
    const size_t BINNED_OFF   = FTH_BYTES;
    const size_t BINNED_BYTES = (size_t)npts * 16;
    const size_t BH_OFF  = BINNED_OFF + ((BINNED_BYTES + 255) & ~(size_t)255);
    const size_t BH_BYTES = (size_t)NBUCKET * nb * sizeof(int);
    const size_t META_OFF = BH_OFF + ((BH_BYTES + 255) & ~(size_t)255);
    const size_t META_BYTES = 2 * NBUCKET * sizeof(int);
    const size_t need_binned = META_OFF + META_BYTES;

    if (ws_size >= need_binned) {
        __half*  fth    = (__half*)d_ws;
        nfloat4* binned = (nfloat4*)((char*)d_ws + BINNED_OFF);
        int*     bhist  = (int*)((char*)d_ws + BH_OFF);
        int*     binSum = (int*)((char*)d_ws + META_OFF);
        int*     binBase = binSum + NBUCKET;

        transpose_feat_h<<<(int)(SPATIAL / 64), 256, 0, stream>>>(feat, fth);
        hist_blocks<<<nb, 256, 0, stream>>>(x, bhist, npts, nb);
        scan_bins<<<NBUCKET, 256, 0, stream>>>(bhist, binSum, nb);
        scan_bin_totals<<<1, 64, 0, stream>>>(binSum, binBase);
        scatter_det<<<nb, 256, 0, stream>>>(x, bhist, binBase, binned, npts, nb);
        trilerp_b<<<gblocks, 256, 0, stream>>>(binned, fth, out, npts);
    } else if (ws_size >= FTH_BYTES) {
        __half* fth = (__half*)d_ws;
        transpose_feat_h<<<(int)(SPATIAL / 64), 256, 0, stream>>>(feat, fth);
        trilerp_h<<<gblocks, 256, 0, stream>>>(x, fth, out, npts);
    } else {
        const int dblocks = (npts * 8 + 255) / 256;
        trilerp_direct<<<dblocks, 256, 0, stream>>>(x, feat, out, npts);
    }
}